// Round 9
// baseline (394.612 us; speedup 1.0000x reference)
//
#include <hip/hip_runtime.h>
#include <hip/hip_fp8.h>
#include <cstdint>
#include <cmath>

// Problem constants
#define B_   4
#define C_   512
#define HW_  4096
#define G_   32
#define CPG_ 16
#define EPS_ 1e-6f
#define SCALE_ 0.04419417382415922f  // 1/sqrt(512)
#define PSCALE_ 0.0625f              // P pre-scale; cancels in acc/rowsum ratio

// ---------------------------------------------------------------------------
// Column permutation (sigma): GEMM epilogues store outputs in the MFMA
// C-layout packed order. Within each 64-col group, stored position
// p = fr*4 + j holds true column c = j*16 + fr  (fr in [0,16), j in [0,4)).
// Invariant under contraction as long as producer & consumer agree.
// The fp8 GEMMs (sexp, pv) read rows directly; a fragment's k-content is the
// raw global bytes, so A/B pair byte-for-byte and sigma cancels exactly.
// ---------------------------------------------------------------------------

typedef __bf16 bf16_t;
typedef __bf16 bf16x8 __attribute__((ext_vector_type(8)));
typedef __bf16 bf16x4 __attribute__((ext_vector_type(4)));
typedef float  f32x4  __attribute__((ext_vector_type(4)));
typedef int    i32x4  __attribute__((ext_vector_type(4)));
typedef int    i32x8  __attribute__((ext_vector_type(8)));
typedef unsigned int u32;
typedef __hip_fp8_e4m3 fp8_t;  // OCP e4m3fn on gfx950

// Async global->LDS copy, 16B per lane. LDS dest is wave-uniform base + lane*16.
__device__ __forceinline__ void cp16(const void* g, void* l) {
  __builtin_amdgcn_global_load_lds((__attribute__((address_space(1))) u32*)(g),
                                   (__attribute__((address_space(3))) u32*)(l),
                                   16, 0, 0);
}

__device__ __forceinline__ void zero_acc(f32x4 acc[4][4]) {
  f32x4 z = {0.f, 0.f, 0.f, 0.f};
#pragma unroll
  for (int i = 0; i < 4; ++i)
#pragma unroll
    for (int j = 0; j < 4; ++j) acc[i][j] = z;
}

// BT GEMM mainloop (bf16, BK=64): C[m][n] = sum_k A[m][k]*B[n][k], K contiguous.
// 128x128 tile, 256 threads = 4 waves, each wave 64x64 via 4x4 MFMA 16x16x32.
// Chunk-rotation swizzle keeps staging and b128 reads at the LDS bank floor.
__device__ __forceinline__ void gemm_bt64(const bf16_t* __restrict__ A,
                                          const bf16_t* __restrict__ B,
                                          int K, int lda, int ldb,
                                          f32x4 acc[4][4]) {
  __shared__ __align__(16) bf16_t As[128 * 64];
  __shared__ __align__(16) bf16_t Bs[128 * 64];
  const int tid  = threadIdx.x;
  const int wave = tid >> 6;
  const int lane = tid & 63;
  const int wm = (wave >> 1) * 64;
  const int wn = (wave & 1) * 64;
  const int srow = lane >> 3;                   // 0..7 within call
  const int gch  = ((lane & 7) - srow) & 7;     // rotated global chunk
  const bf16_t* gA = A + (size_t)(wave * 32 + srow) * lda + gch * 8;
  const bf16_t* gB = B + (size_t)(wave * 32 + srow) * ldb + gch * 8;
  bf16_t* lA = As + wave * 32 * 64;             // wave-uniform LDS base
  bf16_t* lB = Bs + wave * 32 * 64;
  const int fr = lane & 15;                     // m (or n) within 16-tile
  const int q  = lane >> 4;
  const int eo0 = ((q + fr) & 7) * 8;           // rotated offs, halves 0/1
  const int eo1 = ((q + 4 + fr) & 7) * 8;

  for (int k0 = 0; k0 < K; k0 += 64) {
#pragma unroll
    for (int cc = 0; cc < 4; ++cc) {
      cp16(gA + (size_t)(cc * 8) * lda, lA + cc * 512);
      cp16(gB + (size_t)(cc * 8) * ldb, lB + cc * 512);
    }
    gA += 64; gB += 64;
    __syncthreads();
#pragma unroll
    for (int h = 0; h < 2; ++h) {
      const int eo = h ? eo1 : eo0;
      bf16x8 a[4], b[4];
#pragma unroll
      for (int i = 0; i < 4; ++i)
        a[i] = *(const bf16x8*)(As + (wm + i * 16 + fr) * 64 + eo);
#pragma unroll
      for (int j = 0; j < 4; ++j)
        b[j] = *(const bf16x8*)(Bs + (wn + j * 16 + fr) * 64 + eo);
#pragma unroll
      for (int i = 0; i < 4; ++i)
#pragma unroll
        for (int j = 0; j < 4; ++j)
          acc[i][j] = __builtin_amdgcn_mfma_f32_16x16x32_bf16(a[i], b[j], acc[i][j], 0, 0, 0);
    }
    __syncthreads();
  }
}

// ---------------- small prep kernels ----------------

// wqkv: plain cast (its k-dim is the un-permuted input c).
// wproj: stored with sigma-permuted c columns to match hmT's packed layout.
__global__ void __launch_bounds__(256) cast_w_kernel(const float* __restrict__ qkv_w,
                                                     const float* __restrict__ proj_w,
                                                     bf16_t* __restrict__ wqkv,
                                                     bf16_t* __restrict__ wproj) {
  int idx = blockIdx.x * 256 + threadIdx.x;
  const int nq = 1536 * 512;
  if (idx < nq) {
    wqkv[idx] = (bf16_t)qkv_w[idx];
  } else {
    int t = idx - nq;          // o*512 + p
    int p = t & 511;
    int off = p & 63;
    int c = (p & ~63) + ((off & 3) << 4) + (off >> 2);  // sigma(p)
    wproj[t] = (bf16_t)proj_w[(t & ~511) + c];
  }
}

// Partial GroupNorm stats: 8 hw-chunks per group -> 1024 blocks, 2 atomics each.
// stats holds raw (sum, sumsq); norm_tr derives mean/rstd inline.
__global__ void __launch_bounds__(256) gn_partial_kernel(const float* __restrict__ x,
                                                         float* __restrict__ stats) {
  __shared__ float rs[256], rss[256];
  const int bg = blockIdx.x >> 3;       // group id 0..127
  const int ch = blockIdx.x & 7;        // hw chunk 0..7
  const float4* base = (const float4*)(x + (size_t)bg * (CPG_ * HW_)) +
                       (size_t)ch * (CPG_ * HW_ / 4 / 8);
  float s = 0.f, ss = 0.f;
  for (int i = threadIdx.x; i < CPG_ * HW_ / 4 / 8; i += 256) {
    float4 v = base[i];
    s  += v.x + v.y + v.z + v.w;
    ss += v.x * v.x + v.y * v.y + v.z * v.z + v.w * v.w;
  }
  rs[threadIdx.x] = s; rss[threadIdx.x] = ss;
  __syncthreads();
  for (int st = 128; st > 0; st >>= 1) {
    if ((int)threadIdx.x < st) {
      rs[threadIdx.x]  += rs[threadIdx.x + st];
      rss[threadIdx.x] += rss[threadIdx.x + st];
    }
    __syncthreads();
  }
  if (threadIdx.x == 0) {
    atomicAdd(&stats[bg * 2 + 0], rs[0]);
    atomicAdd(&stats[bg * 2 + 1], rss[0]);
  }
}

// normalize + transpose: x[b][c][i] (fp32) -> xnT[b][i][c] (bf16)
// Derives mean/rstd from raw (sum, sumsq) inline (gn_final fused away).
__global__ void __launch_bounds__(256) norm_tr_kernel(const float* __restrict__ x,
                                                      const float* __restrict__ stats,
                                                      const float* __restrict__ nw,
                                                      const float* __restrict__ nb,
                                                      bf16_t* __restrict__ xnT) {
  __shared__ float tile[64][65];
  const int b  = blockIdx.z;
  const int i0 = blockIdx.x * 64;   // hw
  const int c0 = blockIdx.y * 64;   // channel
  const int tx = threadIdx.x & 63;
  const int ty = threadIdx.x >> 6;  // 0..3
  const int cbase = c0 + ty * 16;
  const int g = cbase >> 4;         // group const across r (16 channels per ty)
  const float inv = 1.f / (float)(CPG_ * HW_);
  const float sum  = stats[(b * G_ + g) * 2 + 0];
  const float ssum = stats[(b * G_ + g) * 2 + 1];
  const float mean = sum * inv;
  const float rstd = rsqrtf(ssum * inv - mean * mean + EPS_);
#pragma unroll
  for (int r = 0; r < 16; ++r) {
    const int c = cbase + r;
    float v = x[((size_t)b * C_ + c) * HW_ + i0 + tx];
    tile[ty * 16 + r][tx] = (v - mean) * rstd * nw[c] + nb[c];
  }
  __syncthreads();
#pragma unroll
  for (int r = 0; r < 16; ++r) {
    const int il = ty * 16 + r;
    xnT[((size_t)b * HW_ + i0 + il) * C_ + c0 + tx] = (bf16_t)tile[tx][il];
  }
}

// ---------------- GEMM kernels ----------------

// QKt8[b][i][sigma-pos o] = fp8( xnT . wqkv + bias ); packed dword stores.
__global__ void __launch_bounds__(256) qk_gemm_kernel(const bf16_t* __restrict__ xnT,
                                                      const bf16_t* __restrict__ wqkv,
                                                      const float* __restrict__ qkv_b,
                                                      fp8_t* __restrict__ QKt8) {
  const int b = blockIdx.z;
  f32x4 acc[4][4]; zero_acc(acc);
  const bf16_t* A  = xnT + ((size_t)b * HW_ + blockIdx.y * 128) * C_;
  const bf16_t* Bp = wqkv + (size_t)blockIdx.x * 128 * C_;
  gemm_bt64(A, Bp, C_, C_, C_, acc);
  const int lane = threadIdx.x & 63, wave = threadIdx.x >> 6;
  const int wm = (wave >> 1) * 64, wn = (wave & 1) * 64;
  const int fr = lane & 15, q = lane >> 4;
  const int r0 = blockIdx.y * 128 + wm + (q << 2);
  const int cb = blockIdx.x * 128 + wn;       // 64-col group base (true & stored)
  float bias[4];
#pragma unroll
  for (int j = 0; j < 4; ++j) bias[j] = qkv_b[cb + fr + j * 16];  // true cols
#pragma unroll
  for (int i = 0; i < 4; ++i)
#pragma unroll
    for (int r = 0; r < 4; ++r) {
      const int row = r0 + i * 16 + r;
      u32 dw = 0;
      dw = (u32)__builtin_amdgcn_cvt_pk_fp8_f32(acc[i][0][r] + bias[0],
                                                acc[i][1][r] + bias[1], (int)dw, false);
      dw = (u32)__builtin_amdgcn_cvt_pk_fp8_f32(acc[i][2][r] + bias[2],
                                                acc[i][3][r] + bias[3], (int)dw, true);
      *(u32*)((unsigned char*)QKt8 + ((size_t)b * HW_ + row) * 1024 + cb + fr * 4) = dw;
    }
}

// V8[b][c][sigma-pos j] = fp8( wqkv_v . xnT + bias ); packed dword stores.
__global__ void __launch_bounds__(256) v_gemm_kernel(const bf16_t* __restrict__ wqkv,
                                                     const bf16_t* __restrict__ xnT,
                                                     const float* __restrict__ qkv_b,
                                                     fp8_t* __restrict__ V8) {
  const int b = blockIdx.z;
  f32x4 acc[4][4]; zero_acc(acc);
  const bf16_t* A  = wqkv + (size_t)(1024 + blockIdx.y * 128) * C_;
  const bf16_t* Bp = xnT + ((size_t)b * HW_ + blockIdx.x * 128) * C_;
  gemm_bt64(A, Bp, C_, C_, C_, acc);
  const int lane = threadIdx.x & 63, wave = threadIdx.x >> 6;
  const int wm = (wave >> 1) * 64, wn = (wave & 1) * 64;
  const int fr = lane & 15, q = lane >> 4;
  const int r0 = blockIdx.y * 128 + wm + (q << 2);
  const int cb = blockIdx.x * 128 + wn;       // hw 64-group base
#pragma unroll
  for (int i = 0; i < 4; ++i)
#pragma unroll
    for (int r = 0; r < 4; ++r) {
      const int row = r0 + i * 16 + r;        // c channel (row of V8)
      const float bias = qkv_b[1024 + row];
      u32 dw = 0;
      dw = (u32)__builtin_amdgcn_cvt_pk_fp8_f32(acc[i][0][r] + bias,
                                                acc[i][1][r] + bias, (int)dw, false);
      dw = (u32)__builtin_amdgcn_cvt_pk_fp8_f32(acc[i][2][r] + bias,
                                                acc[i][3][r] + bias, (int)dw, true);
      *(u32*)((unsigned char*)V8 + ((size_t)b * C_ + row) * HW_ + cb + fr * 4) = dw;
    }
}

// P8[b][i][sigma-pos j] = fp8( PSCALE * exp(scale * q_i.k_j) )
// MX-fp8 16x16x128, NO LDS, NO barriers: each lane loads its 32-B fragments
// straight from global (2x dwordx4, saddr+imm offsets). With the 4-iter loop
// fully unrolled and no barriers, the compiler interleaves next-iter loads
// with current-iter MFMAs (fine-grained vmcnt pipelining). Q/K panels are
// L2-resident (16.7 MB); 2-wave row reuse is served by L1.
__global__ void __launch_bounds__(256) sexp_gemm_kernel(const fp8_t* __restrict__ QKt8,
                                                        fp8_t* __restrict__ P8) {
  const int b = blockIdx.z;
  const unsigned char* QKtb = (const unsigned char*)QKt8 + (size_t)b * HW_ * 1024;
  fp8_t* Pb = P8 + (size_t)b * HW_ * HW_;
  const unsigned char* A  = QKtb + (size_t)blockIdx.y * 128 * 1024;        // Q rows
  const unsigned char* Bg = QKtb + 512 + (size_t)blockIdx.x * 128 * 1024;  // K rows
  f32x4 acc[4][4]; zero_acc(acc);
  const int lane = threadIdx.x & 63, wave = threadIdx.x >> 6;
  const int wm = (wave >> 1) * 64, wn = (wave & 1) * 64;
  const int fr = lane & 15, q = lane >> 4;
  const unsigned char* pa[4];
  const unsigned char* pb[4];
#pragma unroll
  for (int i = 0; i < 4; ++i) pa[i] = A  + (size_t)(wm + i * 16 + fr) * 1024 + q * 32;
#pragma unroll
  for (int j = 0; j < 4; ++j) pb[j] = Bg + (size_t)(wn + j * 16 + fr) * 1024 + q * 32;

#pragma unroll
  for (int kk = 0; kk < 4; ++kk) {  // K = 512 = 4 x 128
    i32x8 a[4], bv[4];
#pragma unroll
    for (int i = 0; i < 4; ++i) a[i]  = *(const i32x8*)(pa[i] + kk * 128);
#pragma unroll
    for (int j = 0; j < 4; ++j) bv[j] = *(const i32x8*)(pb[j] + kk * 128);
#pragma unroll
    for (int i = 0; i < 4; ++i)
#pragma unroll
      for (int j = 0; j < 4; ++j)
        acc[i][j] = __builtin_amdgcn_mfma_scale_f32_16x16x128_f8f6f4(
            a[i], bv[j], acc[i][j], 0, 0, 0, 0x7F, 0, 0x7F);
  }

  const int r0 = blockIdx.y * 128 + wm + (q << 2);
  const int cb = blockIdx.x * 128 + wn;       // j 64-group base
#pragma unroll
  for (int i = 0; i < 4; ++i)
#pragma unroll
    for (int r = 0; r < 4; ++r) {
      const int row = r0 + i * 16 + r;
      float e0 = __expf(acc[i][0][r] * SCALE_) * PSCALE_;
      float e1 = __expf(acc[i][1][r] * SCALE_) * PSCALE_;
      float e2 = __expf(acc[i][2][r] * SCALE_) * PSCALE_;
      float e3 = __expf(acc[i][3][r] * SCALE_) * PSCALE_;
      u32 dw = 0;
      dw = (u32)__builtin_amdgcn_cvt_pk_fp8_f32(e0, e1, (int)dw, false);
      dw = (u32)__builtin_amdgcn_cvt_pk_fp8_f32(e2, e3, (int)dw, true);
      *(u32*)((unsigned char*)Pb + (size_t)row * HW_ + cb + fr * 4) = dw;
    }
}

// hmT[b][i][sigma-pos c] = (sum_j P8 * V8) / rowsum(P8)   (PSCALE cancels)
// MX-fp8 16x16x128, NO LDS / barriers (direct fragment loads as in sexp).
// Row sums via ones-vector MFMA on the same quantized A fragments.
// XCD-aware block remap keeps the 4 c-panel blocks sharing a P row-panel
// dispatch-adjacent for L2 locality.
__global__ void __launch_bounds__(256) pv_gemm_kernel(const fp8_t* __restrict__ P8,
                                                      const fp8_t* __restrict__ V8,
                                                      bf16_t* __restrict__ hmT) {
  const int n   = blockIdx.x;
  const int xcd = n & 7;           // XCD (round-robin heuristic)
  const int p   = n >> 3;          // 0..63, position within XCD
  const int xb  = p & 3;           // C panel (fastest -> adjacent blocks share P)
  const int grp = xcd * 16 + (p >> 2);  // 0..127 = (y,z) group
  const int yb  = grp & 31;        // HW panel
  const int b   = grp >> 5;        // batch

  const unsigned char* A  = (const unsigned char*)P8 + (size_t)b * HW_ * HW_ +
                            (size_t)yb * 128 * HW_;
  const unsigned char* Bg = (const unsigned char*)V8 + (size_t)b * C_ * HW_ +
                            (size_t)xb * 128 * HW_;
  bf16_t* hmTb = hmT + (size_t)b * HW_ * C_;

  f32x4 acc[4][4]; zero_acc(acc);
  f32x4 accl[4];
  {
    f32x4 z = {0.f, 0.f, 0.f, 0.f};
#pragma unroll
    for (int i = 0; i < 4; ++i) accl[i] = z;
  }
  const int lane = threadIdx.x & 63, wave = threadIdx.x >> 6;
  const int wm = (wave >> 1) * 64, wn = (wave & 1) * 64;
  const int fr = lane & 15, q = lane >> 4;
  const unsigned char* pa[4];
  const unsigned char* pb[4];
#pragma unroll
  for (int i = 0; i < 4; ++i) pa[i] = A  + (size_t)(wm + i * 16 + fr) * HW_ + q * 32;
#pragma unroll
  for (int j = 0; j < 4; ++j) pb[j] = Bg + (size_t)(wn + j * 16 + fr) * HW_ + q * 32;
  const i32x8 vones = {0x38383838, 0x38383838, 0x38383838, 0x38383838,
                       0x38383838, 0x38383838, 0x38383838, 0x38383838};

#pragma unroll 4
  for (int kk = 0; kk < 32; ++kk) {  // K = 4096 = 32 x 128
    i32x8 a[4], bv[4];
#pragma unroll
    for (int i = 0; i < 4; ++i) a[i]  = *(const i32x8*)(pa[i] + kk * 128);
#pragma unroll
    for (int j = 0; j < 4; ++j) bv[j] = *(const i32x8*)(pb[j] + kk * 128);
#pragma unroll
    for (int i = 0; i < 4; ++i) {
#pragma unroll
      for (int j = 0; j < 4; ++j)
        acc[i][j] = __builtin_amdgcn_mfma_scale_f32_16x16x128_f8f6f4(
            a[i], bv[j], acc[i][j], 0, 0, 0, 0x7F, 0, 0x7F);
      accl[i] = __builtin_amdgcn_mfma_scale_f32_16x16x128_f8f6f4(
          a[i], vones, accl[i], 0, 0, 0, 0x7F, 0, 0x7F);
    }
  }

  const int r0 = yb * 128 + wm + (q << 2);
  const int cb = xb * 128 + wn;   // c 64-group base (stored sigma-packed)
#pragma unroll
  for (int i = 0; i < 4; ++i)
#pragma unroll
    for (int r = 0; r < 4; ++r) {
      const int row = r0 + i * 16 + r;
      const float rl = 1.f / accl[i][r];
      bf16x4 o;
#pragma unroll
      for (int j = 0; j < 4; ++j) o[j] = (bf16_t)(acc[i][j][r] * rl);
      *(bf16x4*)(hmTb + (size_t)row * C_ + cb + fr * 4) = o;
    }
}

// out[b][o][i] = x[b][o][i] + proj_b[o] + wproj(sigma) . hmT(sigma)
__global__ void __launch_bounds__(256) proj_gemm_kernel(const bf16_t* __restrict__ wproj,
                                                        const bf16_t* __restrict__ hmT,
                                                        const float* __restrict__ proj_b,
                                                        const float* __restrict__ x,
                                                        float* __restrict__ out) {
  const int b = blockIdx.z;
  f32x4 acc[4][4]; zero_acc(acc);
  const bf16_t* A  = wproj + (size_t)blockIdx.y * 128 * C_;
  const bf16_t* Bp = hmT + ((size_t)b * HW_ + blockIdx.x * 128) * C_;
  gemm_bt64(A, Bp, C_, C_, C_, acc);
  const int lane = threadIdx.x & 63, wave = threadIdx.x >> 6;
  const int wm = (wave >> 1) * 64, wn = (wave & 1) * 64;
  const int r0 = blockIdx.y * 128 + wm + ((lane >> 4) << 2);
  const int c0 = blockIdx.x * 128 + wn + (lane & 15);
#pragma unroll
  for (int i = 0; i < 4; ++i)
#pragma unroll
    for (int r = 0; r < 4; ++r) {
      const int row = r0 + i * 16 + r;
      const float bias = proj_b[row];
#pragma unroll
      for (int j = 0; j < 4; ++j) {
        const int col = c0 + j * 16;
        const size_t idx = ((size_t)b * C_ + row) * HW_ + col;
        out[idx] = x[idx] + bias + acc[i][j][r];
      }
    }
}

// ---------------- launch ----------------
// Workspace layout (bytes), total ~128 MB:
//   wqkv  bf16 [1536][512]            1,572,864
//   wproj bf16 [512][512] (sigma)       524,288
//   stats f32  [128][2]                   1,024
//   xnT   bf16 [4][4096][512]        16,777,216
//   QKt8  fp8  [4][4096][1024](sig)  16,777,216
//   V8    fp8  [4][512][4096] (sig)   8,388,608
//   hmT   bf16 [4][4096][512] (sig)  16,777,216
//   P8    fp8  [4][4096][4096](sig)  67,108,864
extern "C" void kernel_launch(void* const* d_in, const int* in_sizes, int n_in,
                              void* d_out, int out_size, void* d_ws, size_t ws_size,
                              hipStream_t stream) {
  const float* x      = (const float*)d_in[0];
  const float* norm_w = (const float*)d_in[1];
  const float* norm_b = (const float*)d_in[2];
  const float* qkv_w  = (const float*)d_in[3];
  const float* qkv_b  = (const float*)d_in[4];
  const float* proj_w = (const float*)d_in[5];
  const float* proj_b = (const float*)d_in[6];
  float* out = (float*)d_out;

  char* ws = (char*)d_ws;
  size_t o = 0;
  bf16_t* wqkv  = (bf16_t*)(ws + o); o += (size_t)1536 * 512 * 2;
  bf16_t* wproj = (bf16_t*)(ws + o); o += (size_t)512 * 512 * 2;
  float*  stats = (float*)(ws + o);  o += 128 * 2 * 4;
  bf16_t* xnT   = (bf16_t*)(ws + o); o += (size_t)B_ * HW_ * C_ * 2;
  fp8_t*  QKt8  = (fp8_t*)(ws + o);  o += (size_t)B_ * HW_ * 1024;
  fp8_t*  V8    = (fp8_t*)(ws + o);  o += (size_t)B_ * C_ * HW_;
  bf16_t* hmT   = (bf16_t*)(ws + o); o += (size_t)B_ * HW_ * C_ * 2;
  fp8_t*  P8    = (fp8_t*)(ws + o);  o += (size_t)B_ * HW_ * HW_;

  cast_w_kernel<<<4096, 256, 0, stream>>>(qkv_w, proj_w, wqkv, wproj);
  hipMemsetAsync(stats, 0, 128 * 2 * sizeof(float), stream);
  gn_partial_kernel<<<1024, 256, 0, stream>>>(x, stats);
  norm_tr_kernel<<<dim3(HW_ / 64, C_ / 64, B_), 256, 0, stream>>>(x, stats, norm_w, norm_b, xnT);
  qk_gemm_kernel<<<dim3(1024 / 128, HW_ / 128, B_), 256, 0, stream>>>(xnT, wqkv, qkv_b, QKt8);
  v_gemm_kernel<<<dim3(HW_ / 128, C_ / 128, B_), 256, 0, stream>>>(wqkv, xnT, qkv_b, V8);
  sexp_gemm_kernel<<<dim3(HW_ / 128, HW_ / 128, B_), 256, 0, stream>>>(QKt8, P8);
  pv_gemm_kernel<<<512, 256, 0, stream>>>(P8, V8, hmT);
  proj_gemm_kernel<<<dim3(HW_ / 128, C_ / 128, B_), 256, 0, stream>>>(
      wproj, hmT, proj_b, x, out);
}

// Round 10
// 247.835 us; speedup vs baseline: 1.5922x; 1.5922x over previous
//
#include <hip/hip_runtime.h>
#include <hip/hip_fp8.h>
#include <cstdint>
#include <cmath>

// Problem constants
#define B_   4
#define C_   512
#define HW_  4096
#define G_   32
#define CPG_ 16
#define EPS_ 1e-6f
#define SCALE_ 0.04419417382415922f  // 1/sqrt(512)
#define PSCALE_ 0.0625f              // P pre-scale; cancels in acc/rowsum ratio

// ---------------------------------------------------------------------------
// Column permutation (sigma): GEMM epilogues store outputs in the MFMA
// C-layout packed order. Within each 64-col group, stored position
// p = fr*4 + j holds true column c = j*16 + fr  (fr in [0,16), j in [0,4)).
// Invariant under contraction as long as producer & consumer agree.
//
// NOTE (R8 lesson): the LDS staging in these GEMMs is a COALESCING engine,
// not a reuse cache — cp16 turns row-major panels into per-lane fragment
// order with 1-KB wave transactions. Direct per-lane fragment loads from
// global (R8) scatter into 64x 32-B requests per wave and starve MFMA.
// ---------------------------------------------------------------------------

typedef __bf16 bf16_t;
typedef __bf16 bf16x8 __attribute__((ext_vector_type(8)));
typedef __bf16 bf16x4 __attribute__((ext_vector_type(4)));
typedef float  f32x4  __attribute__((ext_vector_type(4)));
typedef int    i32x4  __attribute__((ext_vector_type(4)));
typedef int    i32x8  __attribute__((ext_vector_type(8)));
typedef unsigned int u32;
typedef __hip_fp8_e4m3 fp8_t;  // OCP e4m3fn on gfx950

// Async global->LDS copy, 16B per lane. LDS dest is wave-uniform base + lane*16.
__device__ __forceinline__ void cp16(const void* g, void* l) {
  __builtin_amdgcn_global_load_lds((__attribute__((address_space(1))) u32*)(g),
                                   (__attribute__((address_space(3))) u32*)(l),
                                   16, 0, 0);
}

__device__ __forceinline__ void zero_acc(f32x4 acc[4][4]) {
  f32x4 z = {0.f, 0.f, 0.f, 0.f};
#pragma unroll
  for (int i = 0; i < 4; ++i)
#pragma unroll
    for (int j = 0; j < 4; ++j) acc[i][j] = z;
}

// BT GEMM mainloop (bf16, BK=64): C[m][n] = sum_k A[m][k]*B[n][k], K contiguous.
// 128x128 tile, 256 threads = 4 waves, each wave 64x64 via 4x4 MFMA 16x16x32.
// Chunk-rotation swizzle keeps staging and b128 reads at the LDS bank floor.
__device__ __forceinline__ void gemm_bt64(const bf16_t* __restrict__ A,
                                          const bf16_t* __restrict__ B,
                                          int K, int lda, int ldb,
                                          f32x4 acc[4][4]) {
  __shared__ __align__(16) bf16_t As[128 * 64];
  __shared__ __align__(16) bf16_t Bs[128 * 64];
  const int tid  = threadIdx.x;
  const int wave = tid >> 6;
  const int lane = tid & 63;
  const int wm = (wave >> 1) * 64;
  const int wn = (wave & 1) * 64;
  const int srow = lane >> 3;                   // 0..7 within call
  const int gch  = ((lane & 7) - srow) & 7;     // rotated global chunk
  const bf16_t* gA = A + (size_t)(wave * 32 + srow) * lda + gch * 8;
  const bf16_t* gB = B + (size_t)(wave * 32 + srow) * ldb + gch * 8;
  bf16_t* lA = As + wave * 32 * 64;             // wave-uniform LDS base
  bf16_t* lB = Bs + wave * 32 * 64;
  const int fr = lane & 15;                     // m (or n) within 16-tile
  const int q  = lane >> 4;
  const int eo0 = ((q + fr) & 7) * 8;           // rotated offs, halves 0/1
  const int eo1 = ((q + 4 + fr) & 7) * 8;

  for (int k0 = 0; k0 < K; k0 += 64) {
#pragma unroll
    for (int cc = 0; cc < 4; ++cc) {
      cp16(gA + (size_t)(cc * 8) * lda, lA + cc * 512);
      cp16(gB + (size_t)(cc * 8) * ldb, lB + cc * 512);
    }
    gA += 64; gB += 64;
    __syncthreads();
#pragma unroll
    for (int h = 0; h < 2; ++h) {
      const int eo = h ? eo1 : eo0;
      bf16x8 a[4], b[4];
#pragma unroll
      for (int i = 0; i < 4; ++i)
        a[i] = *(const bf16x8*)(As + (wm + i * 16 + fr) * 64 + eo);
#pragma unroll
      for (int j = 0; j < 4; ++j)
        b[j] = *(const bf16x8*)(Bs + (wn + j * 16 + fr) * 64 + eo);
#pragma unroll
      for (int i = 0; i < 4; ++i)
#pragma unroll
        for (int j = 0; j < 4; ++j)
          acc[i][j] = __builtin_amdgcn_mfma_f32_16x16x32_bf16(a[i], b[j], acc[i][j], 0, 0, 0);
    }
    __syncthreads();
  }
}

// MX-fp8 BT GEMM mainloop (BK=128): one mfma_scale_f32_16x16x128_f8f6f4 per
// 16x16 tile-pair per k-iter, unit scales (e8m0 0x7F = 1.0, fmt 0 = e4m3).
// LDS rows are 128 B (8 chunks); chunk-rotation swizzle mod 8 keeps staging
// and the paired ds_read_b128 fragment reads at the LDS bank floor.
// ROWSUM adds a ones-vector MFMA per a-fragment: accl[i][r] = rowsum(A row).
template <bool ROWSUM>
__device__ __forceinline__ void gemm_bt_mx(const unsigned char* __restrict__ A,
                                           const unsigned char* __restrict__ B,
                                           int K, int lda, int ldb,
                                           f32x4 acc[4][4], f32x4 accl[4]) {
  __shared__ __align__(16) unsigned char As[128 * 128];
  __shared__ __align__(16) unsigned char Bs[128 * 128];
  const int tid  = threadIdx.x;
  const int wave = tid >> 6;
  const int lane = tid & 63;
  const int wm = (wave >> 1) * 64;
  const int wn = (wave & 1) * 64;
  // staging: per cp16 call lane covers row (lane>>3), LDS chunk (lane&7);
  // rotation: LDS chunk c of row r holds global chunk (c - r) & 7.
  const int srow = lane >> 3;
  const int gch  = ((lane & 7) - srow) & 7;
  const unsigned char* gA = A + (size_t)(wave * 32 + srow) * lda + gch * 16;
  const unsigned char* gB = B + (size_t)(wave * 32 + srow) * ldb + gch * 16;
  unsigned char* lA = As + wave * 32 * 128;
  unsigned char* lB = Bs + wave * 32 * 128;
  const int fr = lane & 15;
  const int q  = lane >> 4;
  // lane wants global chunks 2q, 2q+1 of its row (32 B = K-128 fragment)
  const int co0 = ((2 * q     + fr) & 7) * 16;
  const int co1 = ((2 * q + 1 + fr) & 7) * 16;
  const i32x8 vones = {0x38383838, 0x38383838, 0x38383838, 0x38383838,
                       0x38383838, 0x38383838, 0x38383838, 0x38383838};

  for (int k0 = 0; k0 < K; k0 += 128) {
#pragma unroll
    for (int cc = 0; cc < 4; ++cc) {
      cp16(gA + (size_t)(cc * 8) * lda, lA + cc * 1024);
      cp16(gB + (size_t)(cc * 8) * ldb, lB + cc * 1024);
    }
    gA += 128; gB += 128;
    __syncthreads();
    i32x8 a[4], b[4];
#pragma unroll
    for (int i = 0; i < 4; ++i) {
      const int ro = (wm + i * 16 + fr) * 128;
      i32x4 lo = *(const i32x4*)(As + ro + co0);
      i32x4 hi = *(const i32x4*)(As + ro + co1);
      a[i] = __builtin_shufflevector(lo, hi, 0, 1, 2, 3, 4, 5, 6, 7);
    }
#pragma unroll
    for (int j = 0; j < 4; ++j) {
      const int ro = (wn + j * 16 + fr) * 128;
      i32x4 lo = *(const i32x4*)(Bs + ro + co0);
      i32x4 hi = *(const i32x4*)(Bs + ro + co1);
      b[j] = __builtin_shufflevector(lo, hi, 0, 1, 2, 3, 4, 5, 6, 7);
    }
#pragma unroll
    for (int i = 0; i < 4; ++i) {
#pragma unroll
      for (int j = 0; j < 4; ++j)
        acc[i][j] = __builtin_amdgcn_mfma_scale_f32_16x16x128_f8f6f4(
            a[i], b[j], acc[i][j], 0, 0, 0, 0x7F, 0, 0x7F);
      if (ROWSUM)
        accl[i] = __builtin_amdgcn_mfma_scale_f32_16x16x128_f8f6f4(
            a[i], vones, accl[i], 0, 0, 0, 0x7F, 0, 0x7F);
    }
    __syncthreads();
  }
}

// ---------------- small prep kernels ----------------

// wqkv: plain cast (its k-dim is the un-permuted input c).
// wproj: stored with sigma-permuted c columns to match hmT's packed layout.
__global__ void __launch_bounds__(256) cast_w_kernel(const float* __restrict__ qkv_w,
                                                     const float* __restrict__ proj_w,
                                                     bf16_t* __restrict__ wqkv,
                                                     bf16_t* __restrict__ wproj) {
  int idx = blockIdx.x * 256 + threadIdx.x;
  const int nq = 1536 * 512;
  if (idx < nq) {
    wqkv[idx] = (bf16_t)qkv_w[idx];
  } else {
    int t = idx - nq;          // o*512 + p
    int p = t & 511;
    int off = p & 63;
    int c = (p & ~63) + ((off & 3) << 4) + (off >> 2);  // sigma(p)
    wproj[t] = (bf16_t)proj_w[(t & ~511) + c];
  }
}

// Partial GroupNorm stats: 8 hw-chunks per group -> 1024 blocks, 2 atomics each.
// stats holds raw (sum, sumsq); norm_tr derives mean/rstd inline.
__global__ void __launch_bounds__(256) gn_partial_kernel(const float* __restrict__ x,
                                                         float* __restrict__ stats) {
  __shared__ float rs[256], rss[256];
  const int bg = blockIdx.x >> 3;       // group id 0..127
  const int ch = blockIdx.x & 7;        // hw chunk 0..7
  const float4* base = (const float4*)(x + (size_t)bg * (CPG_ * HW_)) +
                       (size_t)ch * (CPG_ * HW_ / 4 / 8);
  float s = 0.f, ss = 0.f;
  for (int i = threadIdx.x; i < CPG_ * HW_ / 4 / 8; i += 256) {
    float4 v = base[i];
    s  += v.x + v.y + v.z + v.w;
    ss += v.x * v.x + v.y * v.y + v.z * v.z + v.w * v.w;
  }
  rs[threadIdx.x] = s; rss[threadIdx.x] = ss;
  __syncthreads();
  for (int st = 128; st > 0; st >>= 1) {
    if ((int)threadIdx.x < st) {
      rs[threadIdx.x]  += rs[threadIdx.x + st];
      rss[threadIdx.x] += rss[threadIdx.x + st];
    }
    __syncthreads();
  }
  if (threadIdx.x == 0) {
    atomicAdd(&stats[bg * 2 + 0], rs[0]);
    atomicAdd(&stats[bg * 2 + 1], rss[0]);
  }
}

// normalize + transpose: x[b][c][i] (fp32) -> xnT[b][i][c] (bf16)
// Derives mean/rstd from raw (sum, sumsq) inline.
__global__ void __launch_bounds__(256) norm_tr_kernel(const float* __restrict__ x,
                                                      const float* __restrict__ stats,
                                                      const float* __restrict__ nw,
                                                      const float* __restrict__ nb,
                                                      bf16_t* __restrict__ xnT) {
  __shared__ float tile[64][65];
  const int b  = blockIdx.z;
  const int i0 = blockIdx.x * 64;   // hw
  const int c0 = blockIdx.y * 64;   // channel
  const int tx = threadIdx.x & 63;
  const int ty = threadIdx.x >> 6;  // 0..3
  const int cbase = c0 + ty * 16;
  const int g = cbase >> 4;         // group const across r (16 channels per ty)
  const float inv = 1.f / (float)(CPG_ * HW_);
  const float sum  = stats[(b * G_ + g) * 2 + 0];
  const float ssum = stats[(b * G_ + g) * 2 + 1];
  const float mean = sum * inv;
  const float rstd = rsqrtf(ssum * inv - mean * mean + EPS_);
#pragma unroll
  for (int r = 0; r < 16; ++r) {
    const int c = cbase + r;
    float v = x[((size_t)b * C_ + c) * HW_ + i0 + tx];
    tile[ty * 16 + r][tx] = (v - mean) * rstd * nw[c] + nb[c];
  }
  __syncthreads();
#pragma unroll
  for (int r = 0; r < 16; ++r) {
    const int il = ty * 16 + r;
    xnT[((size_t)b * HW_ + i0 + il) * C_ + c0 + tx] = (bf16_t)tile[tx][il];
  }
}

// ---------------- GEMM kernels ----------------

// QKt8[b][i][sigma-pos o] = fp8( xnT . wqkv + bias ); packed dword stores.
__global__ void __launch_bounds__(256) qk_gemm_kernel(const bf16_t* __restrict__ xnT,
                                                      const bf16_t* __restrict__ wqkv,
                                                      const float* __restrict__ qkv_b,
                                                      fp8_t* __restrict__ QKt8) {
  const int b = blockIdx.z;
  f32x4 acc[4][4]; zero_acc(acc);
  const bf16_t* A  = xnT + ((size_t)b * HW_ + blockIdx.y * 128) * C_;
  const bf16_t* Bp = wqkv + (size_t)blockIdx.x * 128 * C_;
  gemm_bt64(A, Bp, C_, C_, C_, acc);
  const int lane = threadIdx.x & 63, wave = threadIdx.x >> 6;
  const int wm = (wave >> 1) * 64, wn = (wave & 1) * 64;
  const int fr = lane & 15, q = lane >> 4;
  const int r0 = blockIdx.y * 128 + wm + (q << 2);
  const int cb = blockIdx.x * 128 + wn;       // 64-col group base (true & stored)
  float bias[4];
#pragma unroll
  for (int j = 0; j < 4; ++j) bias[j] = qkv_b[cb + fr + j * 16];  // true cols
#pragma unroll
  for (int i = 0; i < 4; ++i)
#pragma unroll
    for (int r = 0; r < 4; ++r) {
      const int row = r0 + i * 16 + r;
      u32 dw = 0;
      dw = (u32)__builtin_amdgcn_cvt_pk_fp8_f32(acc[i][0][r] + bias[0],
                                                acc[i][1][r] + bias[1], (int)dw, false);
      dw = (u32)__builtin_amdgcn_cvt_pk_fp8_f32(acc[i][2][r] + bias[2],
                                                acc[i][3][r] + bias[3], (int)dw, true);
      *(u32*)((unsigned char*)QKt8 + ((size_t)b * HW_ + row) * 1024 + cb + fr * 4) = dw;
    }
}

// V8[b][c][sigma-pos j] = fp8( wqkv_v . xnT + bias ); packed dword stores.
__global__ void __launch_bounds__(256) v_gemm_kernel(const bf16_t* __restrict__ wqkv,
                                                     const bf16_t* __restrict__ xnT,
                                                     const float* __restrict__ qkv_b,
                                                     fp8_t* __restrict__ V8) {
  const int b = blockIdx.z;
  f32x4 acc[4][4]; zero_acc(acc);
  const bf16_t* A  = wqkv + (size_t)(1024 + blockIdx.y * 128) * C_;
  const bf16_t* Bp = xnT + ((size_t)b * HW_ + blockIdx.x * 128) * C_;
  gemm_bt64(A, Bp, C_, C_, C_, acc);
  const int lane = threadIdx.x & 63, wave = threadIdx.x >> 6;
  const int wm = (wave >> 1) * 64, wn = (wave & 1) * 64;
  const int fr = lane & 15, q = lane >> 4;
  const int r0 = blockIdx.y * 128 + wm + (q << 2);
  const int cb = blockIdx.x * 128 + wn;       // hw 64-group base
#pragma unroll
  for (int i = 0; i < 4; ++i)
#pragma unroll
    for (int r = 0; r < 4; ++r) {
      const int row = r0 + i * 16 + r;        // c channel (row of V8)
      const float bias = qkv_b[1024 + row];
      u32 dw = 0;
      dw = (u32)__builtin_amdgcn_cvt_pk_fp8_f32(acc[i][0][r] + bias,
                                                acc[i][1][r] + bias, (int)dw, false);
      dw = (u32)__builtin_amdgcn_cvt_pk_fp8_f32(acc[i][2][r] + bias,
                                                acc[i][3][r] + bias, (int)dw, true);
      *(u32*)((unsigned char*)V8 + ((size_t)b * C_ + row) * HW_ + cb + fr * 4) = dw;
    }
}

// P8[b][i][sigma-pos j] = fp8( PSCALE * exp(scale * q_i.k_j) ); MX-fp8 GEMM.
// XCD-aware 1-D grid: the 32 K-panel blocks sharing a Q row-panel are
// dispatch-adjacent on one XCD (QKt8 panels stay L2-hot per XCD).
__global__ void __launch_bounds__(256) sexp_gemm_kernel(const fp8_t* __restrict__ QKt8,
                                                        fp8_t* __restrict__ P8) {
  const int n   = blockIdx.x;            // 4096 blocks
  const int xcd = n & 7;
  const int p   = n >> 3;                // 0..511 within XCD
  const int xb  = p & 31;                // K panel (fastest -> share Q panel)
  const int grp = xcd * 16 + (p >> 5);   // 0..127 = (yb, b) combo
  const int yb  = grp & 31;              // Q panel
  const int b   = grp >> 5;              // batch

  const unsigned char* QKtb = (const unsigned char*)QKt8 + (size_t)b * HW_ * 1024;
  fp8_t* Pb = P8 + (size_t)b * HW_ * HW_;
  f32x4 acc[4][4]; zero_acc(acc);
  const unsigned char* A  = QKtb + (size_t)yb * 128 * 1024;        // Q rows
  const unsigned char* Bp = QKtb + 512 + (size_t)xb * 128 * 1024;  // K rows
  gemm_bt_mx<false>(A, Bp, 512, 1024, 1024, acc, nullptr);
  const int lane = threadIdx.x & 63, wave = threadIdx.x >> 6;
  const int wm = (wave >> 1) * 64, wn = (wave & 1) * 64;
  const int fr = lane & 15, q = lane >> 4;
  const int r0 = yb * 128 + wm + (q << 2);
  const int cb = xb * 128 + wn;          // j 64-group base
#pragma unroll
  for (int i = 0; i < 4; ++i)
#pragma unroll
    for (int r = 0; r < 4; ++r) {
      const int row = r0 + i * 16 + r;
      float e0 = __expf(acc[i][0][r] * SCALE_) * PSCALE_;
      float e1 = __expf(acc[i][1][r] * SCALE_) * PSCALE_;
      float e2 = __expf(acc[i][2][r] * SCALE_) * PSCALE_;
      float e3 = __expf(acc[i][3][r] * SCALE_) * PSCALE_;
      u32 dw = 0;
      dw = (u32)__builtin_amdgcn_cvt_pk_fp8_f32(e0, e1, (int)dw, false);
      dw = (u32)__builtin_amdgcn_cvt_pk_fp8_f32(e2, e3, (int)dw, true);
      *(u32*)((unsigned char*)Pb + (size_t)row * HW_ + cb + fr * 4) = dw;
    }
}

// hmT[b][i][sigma-pos c] = (sum_j P8 * V8) / rowsum(P8)   (PSCALE cancels)
// MX-fp8 GEMM with ones-MFMA row sums; XCD-aware block remap for P L2 reuse.
__global__ void __launch_bounds__(256) pv_gemm_kernel(const fp8_t* __restrict__ P8,
                                                      const fp8_t* __restrict__ V8,
                                                      bf16_t* __restrict__ hmT) {
  // decode swizzled block id: n = 512 blocks total
  const int n   = blockIdx.x;
  const int xcd = n & 7;           // XCD (round-robin heuristic)
  const int p   = n >> 3;          // 0..63, position within XCD
  const int xb  = p & 3;           // C panel (fastest -> adjacent blocks share P)
  const int grp = xcd * 16 + (p >> 2);  // 0..127 = (y,z) group
  const int yb  = grp & 31;        // HW panel
  const int b   = grp >> 5;        // batch

  const unsigned char* A  = (const unsigned char*)P8 + (size_t)b * HW_ * HW_ +
                            (size_t)yb * 128 * HW_;
  const unsigned char* Bp = (const unsigned char*)V8 + (size_t)b * C_ * HW_ +
                            (size_t)xb * 128 * HW_;
  bf16_t* hmTb = hmT + (size_t)b * HW_ * C_;

  f32x4 acc[4][4]; zero_acc(acc);
  f32x4 accl[4];
  {
    f32x4 z = {0.f, 0.f, 0.f, 0.f};
#pragma unroll
    for (int i = 0; i < 4; ++i) accl[i] = z;
  }
  gemm_bt_mx<true>(A, Bp, HW_, HW_, HW_, acc, accl);

  const int lane = threadIdx.x & 63, wave = threadIdx.x >> 6;
  const int wm = (wave >> 1) * 64, wn = (wave & 1) * 64;
  const int fr = lane & 15, q = lane >> 4;
  const int r0 = yb * 128 + wm + (q << 2);
  const int cb = xb * 128 + wn;   // c 64-group base (stored sigma-packed)
#pragma unroll
  for (int i = 0; i < 4; ++i)
#pragma unroll
    for (int r = 0; r < 4; ++r) {
      const int row = r0 + i * 16 + r;
      const float rl = 1.f / accl[i][r];
      bf16x4 o;
#pragma unroll
      for (int j = 0; j < 4; ++j) o[j] = (bf16_t)(acc[i][j][r] * rl);
      *(bf16x4*)(hmTb + (size_t)row * C_ + cb + fr * 4) = o;
    }
}

// out[b][o][i] = x[b][o][i] + proj_b[o] + wproj(sigma) . hmT(sigma)
__global__ void __launch_bounds__(256) proj_gemm_kernel(const bf16_t* __restrict__ wproj,
                                                        const bf16_t* __restrict__ hmT,
                                                        const float* __restrict__ proj_b,
                                                        const float* __restrict__ x,
                                                        float* __restrict__ out) {
  const int b = blockIdx.z;
  f32x4 acc[4][4]; zero_acc(acc);
  const bf16_t* A  = wproj + (size_t)blockIdx.y * 128 * C_;
  const bf16_t* Bp = hmT + ((size_t)b * HW_ + blockIdx.x * 128) * C_;
  gemm_bt64(A, Bp, C_, C_, C_, acc);
  const int lane = threadIdx.x & 63, wave = threadIdx.x >> 6;
  const int wm = (wave >> 1) * 64, wn = (wave & 1) * 64;
  const int r0 = blockIdx.y * 128 + wm + ((lane >> 4) << 2);
  const int c0 = blockIdx.x * 128 + wn + (lane & 15);
#pragma unroll
  for (int i = 0; i < 4; ++i)
#pragma unroll
    for (int r = 0; r < 4; ++r) {
      const int row = r0 + i * 16 + r;
      const float bias = proj_b[row];
#pragma unroll
      for (int j = 0; j < 4; ++j) {
        const int col = c0 + j * 16;
        const size_t idx = ((size_t)b * C_ + row) * HW_ + col;
        out[idx] = x[idx] + bias + acc[i][j][r];
      }
    }
}

// ---------------- launch ----------------
// Workspace layout (bytes), total ~128 MB:
//   wqkv  bf16 [1536][512]            1,572,864
//   wproj bf16 [512][512] (sigma)       524,288
//   stats f32  [128][2]                   1,024
//   xnT   bf16 [4][4096][512]        16,777,216
//   QKt8  fp8  [4][4096][1024](sig)  16,777,216
//   V8    fp8  [4][512][4096] (sig)   8,388,608
//   hmT   bf16 [4][4096][512] (sig)  16,777,216
//   P8    fp8  [4][4096][4096](sig)  67,108,864
extern "C" void kernel_launch(void* const* d_in, const int* in_sizes, int n_in,
                              void* d_out, int out_size, void* d_ws, size_t ws_size,
                              hipStream_t stream) {
  const float* x      = (const float*)d_in[0];
  const float* norm_w = (const float*)d_in[1];
  const float* norm_b = (const float*)d_in[2];
  const float* qkv_w  = (const float*)d_in[3];
  const float* qkv_b  = (const float*)d_in[4];
  const float* proj_w = (const float*)d_in[5];
  const float* proj_b = (const float*)d_in[6];
  float* out = (float*)d_out;

  char* ws = (char*)d_ws;
  size_t o = 0;
  bf16_t* wqkv  = (bf16_t*)(ws + o); o += (size_t)1536 * 512 * 2;
  bf16_t* wproj = (bf16_t*)(ws + o); o += (size_t)512 * 512 * 2;
  float*  stats = (float*)(ws + o);  o += 128 * 2 * 4;
  bf16_t* xnT   = (bf16_t*)(ws + o); o += (size_t)B_ * HW_ * C_ * 2;
  fp8_t*  QKt8  = (fp8_t*)(ws + o);  o += (size_t)B_ * HW_ * 1024;
  fp8_t*  V8    = (fp8_t*)(ws + o);  o += (size_t)B_ * C_ * HW_;
  bf16_t* hmT   = (bf16_t*)(ws + o); o += (size_t)B_ * HW_ * C_ * 2;
  fp8_t*  P8    = (fp8_t*)(ws + o);  o += (size_t)B_ * HW_ * HW_;

  cast_w_kernel<<<4096, 256, 0, stream>>>(qkv_w, proj_w, wqkv, wproj);
  hipMemsetAsync(stats, 0, 128 * 2 * sizeof(float), stream);
  gn_partial_kernel<<<1024, 256, 0, stream>>>(x, stats);
  norm_tr_kernel<<<dim3(HW_ / 64, C_ / 64, B_), 256, 0, stream>>>(x, stats, norm_w, norm_b, xnT);
  qk_gemm_kernel<<<dim3(1024 / 128, HW_ / 128, B_), 256, 0, stream>>>(xnT, wqkv, qkv_b, QKt8);
  v_gemm_kernel<<<dim3(HW_ / 128, C_ / 128, B_), 256, 0, stream>>>(wqkv, xnT, qkv_b, V8);
  sexp_gemm_kernel<<<4096, 256, 0, stream>>>(QKt8, P8);
  pv_gemm_kernel<<<512, 256, 0, stream>>>(P8, V8, hmT);
  proj_gemm_kernel<<<dim3(HW_ / 128, C_ / 128, B_), 256, 0, stream>>>(
      wproj, hmT, proj_b, x, out);
}

// Round 11
// 239.528 us; speedup vs baseline: 1.6475x; 1.0347x over previous
//
#include <hip/hip_runtime.h>
#include <hip/hip_fp8.h>
#include <cstdint>
#include <cmath>

// Problem constants
#define B_   4
#define C_   512
#define HW_  4096
#define G_   32
#define CPG_ 16
#define EPS_ 1e-6f
#define SCALE_ 0.04419417382415922f  // 1/sqrt(512)
#define PSCALE_ 0.0625f              // P pre-scale; cancels in acc/rowsum ratio

// ---------------------------------------------------------------------------
// Column permutation (sigma): GEMM epilogues store outputs in the MFMA
// C-layout packed order. Within each 64-col group, stored position
// p = fr*4 + j holds true column c = j*16 + fr. Invariant under contraction
// as long as producer & consumer agree. Additionally, any fixed byte
// permutation introduced by cvt_pk_fp8 packing cancels: both A and B
// producers use the same idiom, so byte-k of an A row always pairs with
// byte-k of a B row holding the same true k-index.
//
// Weight scaling: fp8 weights are stored x16 (to sit in e4m3's sweet spot);
// the MFMA's e8m0 scale operand 0x7B (= 2^-4) folds the 1/16 back in HW.
// Same trick for hmT8 (x16, scale 2^-4 in proj).
//
// NOTE (R8 lesson): LDS staging here is a COALESCING engine, not a reuse
// cache — cp16 turns row-major panels into fragment order with 1-KB wave
// transactions; direct per-lane global fragment loads starve MFMA.
// ---------------------------------------------------------------------------

typedef __bf16 bf16_t;
typedef __bf16 bf16x8 __attribute__((ext_vector_type(8)));
typedef float  f32x4  __attribute__((ext_vector_type(4)));
typedef int    i32x4  __attribute__((ext_vector_type(4)));
typedef int    i32x8  __attribute__((ext_vector_type(8)));
typedef unsigned int u32;
typedef __hip_fp8_e4m3 fp8_t;  // OCP e4m3fn on gfx950

// Async global->LDS copy, 16B per lane. LDS dest is wave-uniform base + lane*16.
__device__ __forceinline__ void cp16(const void* g, void* l) {
  __builtin_amdgcn_global_load_lds((__attribute__((address_space(1))) u32*)(g),
                                   (__attribute__((address_space(3))) u32*)(l),
                                   16, 0, 0);
}

__device__ __forceinline__ void zero_acc(f32x4 acc[4][4]) {
  f32x4 z = {0.f, 0.f, 0.f, 0.f};
#pragma unroll
  for (int i = 0; i < 4; ++i)
#pragma unroll
    for (int j = 0; j < 4; ++j) acc[i][j] = z;
}

// MX-fp8 BT GEMM mainloop (BK=128): mfma_scale_f32_16x16x128_f8f6f4, fmt 0
// (e4m3), per-operand e8m0 scales SA/SB (0x7F = 1.0, 0x7B = 2^-4).
// LDS rows are 128 B (8 chunks); chunk-rotation swizzle mod 8 keeps staging
// and the paired ds_read_b128 fragment reads at the LDS bank floor.
// ROWSUM adds a ones-vector MFMA per a-fragment: accl[i][r] = rowsum(A row).
template <bool ROWSUM, int SA = 0x7F, int SB = 0x7F>
__device__ __forceinline__ void gemm_bt_mx(const unsigned char* __restrict__ A,
                                           const unsigned char* __restrict__ B,
                                           int K, int lda, int ldb,
                                           f32x4 acc[4][4], f32x4 accl[4]) {
  __shared__ __align__(16) unsigned char As[128 * 128];
  __shared__ __align__(16) unsigned char Bs[128 * 128];
  const int tid  = threadIdx.x;
  const int wave = tid >> 6;
  const int lane = tid & 63;
  const int wm = (wave >> 1) * 64;
  const int wn = (wave & 1) * 64;
  // staging: per cp16 call lane covers row (lane>>3), LDS chunk (lane&7);
  // rotation: LDS chunk c of row r holds global chunk (c - r) & 7.
  const int srow = lane >> 3;
  const int gch  = ((lane & 7) - srow) & 7;
  const unsigned char* gA = A + (size_t)(wave * 32 + srow) * lda + gch * 16;
  const unsigned char* gB = B + (size_t)(wave * 32 + srow) * ldb + gch * 16;
  unsigned char* lA = As + wave * 32 * 128;
  unsigned char* lB = Bs + wave * 32 * 128;
  const int fr = lane & 15;
  const int q  = lane >> 4;
  // lane wants global chunks 2q, 2q+1 of its row (32 B = K-128 fragment)
  const int co0 = ((2 * q     + fr) & 7) * 16;
  const int co1 = ((2 * q + 1 + fr) & 7) * 16;
  const i32x8 vones = {0x38383838, 0x38383838, 0x38383838, 0x38383838,
                       0x38383838, 0x38383838, 0x38383838, 0x38383838};

  for (int k0 = 0; k0 < K; k0 += 128) {
#pragma unroll
    for (int cc = 0; cc < 4; ++cc) {
      cp16(gA + (size_t)(cc * 8) * lda, lA + cc * 1024);
      cp16(gB + (size_t)(cc * 8) * ldb, lB + cc * 1024);
    }
    gA += 128; gB += 128;
    __syncthreads();
    i32x8 a[4], b[4];
#pragma unroll
    for (int i = 0; i < 4; ++i) {
      const int ro = (wm + i * 16 + fr) * 128;
      i32x4 lo = *(const i32x4*)(As + ro + co0);
      i32x4 hi = *(const i32x4*)(As + ro + co1);
      a[i] = __builtin_shufflevector(lo, hi, 0, 1, 2, 3, 4, 5, 6, 7);
    }
#pragma unroll
    for (int j = 0; j < 4; ++j) {
      const int ro = (wn + j * 16 + fr) * 128;
      i32x4 lo = *(const i32x4*)(Bs + ro + co0);
      i32x4 hi = *(const i32x4*)(Bs + ro + co1);
      b[j] = __builtin_shufflevector(lo, hi, 0, 1, 2, 3, 4, 5, 6, 7);
    }
#pragma unroll
    for (int i = 0; i < 4; ++i) {
#pragma unroll
      for (int j = 0; j < 4; ++j)
        acc[i][j] = __builtin_amdgcn_mfma_scale_f32_16x16x128_f8f6f4(
            a[i], b[j], acc[i][j], 0, 0, 0, SA, 0, SB);
      if (ROWSUM)
        accl[i] = __builtin_amdgcn_mfma_scale_f32_16x16x128_f8f6f4(
            a[i], vones, accl[i], 0, 0, 0, SA, 0, 0x7F);
    }
    __syncthreads();
  }
}

// ---------------- small prep kernels ----------------

// wqkv8 = fp8(qkv_w * 16), plain layout (k-dim = un-permuted input c).
// wproj8 = fp8(proj_w * 16) with sigma-permuted c columns to match hmT8.
// Packed dword stores (4 fp8 per thread-iter).
__global__ void __launch_bounds__(256) cast_w_kernel(const float* __restrict__ qkv_w,
                                                     const float* __restrict__ proj_w,
                                                     fp8_t* __restrict__ wqkv8,
                                                     fp8_t* __restrict__ wproj8) {
  const int idx = blockIdx.x * 256 + threadIdx.x;   // quad index
  const int t = idx * 4;
  const int nq = 1536 * 512;
  if (t < nq) {
    u32 dw = 0;
    dw = (u32)__builtin_amdgcn_cvt_pk_fp8_f32(qkv_w[t] * 16.f, qkv_w[t + 1] * 16.f, (int)dw, false);
    dw = (u32)__builtin_amdgcn_cvt_pk_fp8_f32(qkv_w[t + 2] * 16.f, qkv_w[t + 3] * 16.f, (int)dw, true);
    *(u32*)((unsigned char*)wqkv8 + t) = dw;
  } else {
    const int tt = t - nq;          // o*512 + p, p multiple of 4
    const int o = tt >> 9;
    const int p = tt & 511;
    float v[4];
#pragma unroll
    for (int e = 0; e < 4; ++e) {
      const int pe = p + e;
      const int off = pe & 63;
      const int c = (pe & ~63) + ((off & 3) << 4) + (off >> 2);  // sigma(pe)
      v[e] = proj_w[(o << 9) + c] * 16.f;
    }
    u32 dw = 0;
    dw = (u32)__builtin_amdgcn_cvt_pk_fp8_f32(v[0], v[1], (int)dw, false);
    dw = (u32)__builtin_amdgcn_cvt_pk_fp8_f32(v[2], v[3], (int)dw, true);
    *(u32*)((unsigned char*)wproj8 + tt) = dw;
  }
}

// Partial GroupNorm stats: 8 hw-chunks per group -> 1024 blocks, 2 atomics each.
// stats holds raw (sum, sumsq); norm_tr derives mean/rstd inline.
__global__ void __launch_bounds__(256) gn_partial_kernel(const float* __restrict__ x,
                                                         float* __restrict__ stats) {
  __shared__ float rs[256], rss[256];
  const int bg = blockIdx.x >> 3;       // group id 0..127
  const int ch = blockIdx.x & 7;        // hw chunk 0..7
  const float4* base = (const float4*)(x + (size_t)bg * (CPG_ * HW_)) +
                       (size_t)ch * (CPG_ * HW_ / 4 / 8);
  float s = 0.f, ss = 0.f;
  for (int i = threadIdx.x; i < CPG_ * HW_ / 4 / 8; i += 256) {
    float4 v = base[i];
    s  += v.x + v.y + v.z + v.w;
    ss += v.x * v.x + v.y * v.y + v.z * v.z + v.w * v.w;
  }
  rs[threadIdx.x] = s; rss[threadIdx.x] = ss;
  __syncthreads();
  for (int st = 128; st > 0; st >>= 1) {
    if ((int)threadIdx.x < st) {
      rs[threadIdx.x]  += rs[threadIdx.x + st];
      rss[threadIdx.x] += rss[threadIdx.x + st];
    }
    __syncthreads();
  }
  if (threadIdx.x == 0) {
    atomicAdd(&stats[bg * 2 + 0], rs[0]);
    atomicAdd(&stats[bg * 2 + 1], rss[0]);
  }
}

// normalize + transpose: x[b][c][i] (fp32) -> xnT8[b][i][c] (fp8, plain order)
// Derives mean/rstd from raw (sum, sumsq) inline. Packed dword stores.
__global__ void __launch_bounds__(256) norm_tr_kernel(const float* __restrict__ x,
                                                      const float* __restrict__ stats,
                                                      const float* __restrict__ nw,
                                                      const float* __restrict__ nb,
                                                      fp8_t* __restrict__ xnT8) {
  __shared__ float tile[64][65];   // [c_off][i_off]
  const int b  = blockIdx.z;
  const int i0 = blockIdx.x * 64;   // hw
  const int c0 = blockIdx.y * 64;   // channel
  const int tx = threadIdx.x & 63;
  const int ty = threadIdx.x >> 6;  // 0..3
  const int cbase = c0 + ty * 16;
  const int g = cbase >> 4;         // group const across r (16 channels per ty)
  const float inv = 1.f / (float)(CPG_ * HW_);
  const float sum  = stats[(b * G_ + g) * 2 + 0];
  const float ssum = stats[(b * G_ + g) * 2 + 1];
  const float mean = sum * inv;
  const float rstd = rsqrtf(ssum * inv - mean * mean + EPS_);
#pragma unroll
  for (int r = 0; r < 16; ++r) {
    const int c = cbase + r;
    float v = x[((size_t)b * C_ + c) * HW_ + i0 + tx];
    tile[ty * 16 + r][tx] = (v - mean) * rstd * nw[c] + nb[c];
  }
  __syncthreads();
  // pack 4 consecutive channels per dword store: thread t covers row il=t>>2,
  // c-quads (t&3)+4m.
  const int il = threadIdx.x >> 2;
  const int q4 = threadIdx.x & 3;
#pragma unroll
  for (int m = 0; m < 4; ++m) {
    const int cq = q4 + m * 4;     // 0..15
    u32 dw = 0;
    dw = (u32)__builtin_amdgcn_cvt_pk_fp8_f32(tile[cq * 4 + 0][il], tile[cq * 4 + 1][il], (int)dw, false);
    dw = (u32)__builtin_amdgcn_cvt_pk_fp8_f32(tile[cq * 4 + 2][il], tile[cq * 4 + 3][il], (int)dw, true);
    *(u32*)((unsigned char*)xnT8 + ((size_t)b * HW_ + i0 + il) * C_ + c0 + cq * 4) = dw;
  }
}

// ---------------- GEMM kernels ----------------

// QKt8[b][i][sigma-pos o] = fp8( xnT8 . wqkv8*2^-4 + bias ); MX GEMM, K=512.
__global__ void __launch_bounds__(256) qk_gemm_kernel(const fp8_t* __restrict__ xnT8,
                                                      const fp8_t* __restrict__ wqkv8,
                                                      const float* __restrict__ qkv_b,
                                                      fp8_t* __restrict__ QKt8) {
  const int b = blockIdx.z;
  f32x4 acc[4][4]; zero_acc(acc);
  const unsigned char* A  = (const unsigned char*)xnT8 + ((size_t)b * HW_ + blockIdx.y * 128) * C_;
  const unsigned char* Bp = (const unsigned char*)wqkv8 + (size_t)blockIdx.x * 128 * C_;
  gemm_bt_mx<false, 0x7F, 0x7B>(A, Bp, C_, C_, C_, acc, nullptr);
  const int lane = threadIdx.x & 63, wave = threadIdx.x >> 6;
  const int wm = (wave >> 1) * 64, wn = (wave & 1) * 64;
  const int fr = lane & 15, q = lane >> 4;
  const int r0 = blockIdx.y * 128 + wm + (q << 2);
  const int cb = blockIdx.x * 128 + wn;       // 64-col group base (true & stored)
  float bias[4];
#pragma unroll
  for (int j = 0; j < 4; ++j) bias[j] = qkv_b[cb + fr + j * 16];  // true cols
#pragma unroll
  for (int i = 0; i < 4; ++i)
#pragma unroll
    for (int r = 0; r < 4; ++r) {
      const int row = r0 + i * 16 + r;
      u32 dw = 0;
      dw = (u32)__builtin_amdgcn_cvt_pk_fp8_f32(acc[i][0][r] + bias[0],
                                                acc[i][1][r] + bias[1], (int)dw, false);
      dw = (u32)__builtin_amdgcn_cvt_pk_fp8_f32(acc[i][2][r] + bias[2],
                                                acc[i][3][r] + bias[3], (int)dw, true);
      *(u32*)((unsigned char*)QKt8 + ((size_t)b * HW_ + row) * 1024 + cb + fr * 4) = dw;
    }
}

// V8[b][c][sigma-pos j] = fp8( wqkv8_v*2^-4 . xnT8 + bias ); MX GEMM, K=512.
__global__ void __launch_bounds__(256) v_gemm_kernel(const fp8_t* __restrict__ wqkv8,
                                                     const fp8_t* __restrict__ xnT8,
                                                     const float* __restrict__ qkv_b,
                                                     fp8_t* __restrict__ V8) {
  const int b = blockIdx.z;
  f32x4 acc[4][4]; zero_acc(acc);
  const unsigned char* A  = (const unsigned char*)wqkv8 + (size_t)(1024 + blockIdx.y * 128) * C_;
  const unsigned char* Bp = (const unsigned char*)xnT8 + ((size_t)b * HW_ + blockIdx.x * 128) * C_;
  gemm_bt_mx<false, 0x7B, 0x7F>(A, Bp, C_, C_, C_, acc, nullptr);
  const int lane = threadIdx.x & 63, wave = threadIdx.x >> 6;
  const int wm = (wave >> 1) * 64, wn = (wave & 1) * 64;
  const int fr = lane & 15, q = lane >> 4;
  const int r0 = blockIdx.y * 128 + wm + (q << 2);
  const int cb = blockIdx.x * 128 + wn;       // hw 64-group base
#pragma unroll
  for (int i = 0; i < 4; ++i)
#pragma unroll
    for (int r = 0; r < 4; ++r) {
      const int row = r0 + i * 16 + r;        // c channel (row of V8)
      const float bias = qkv_b[1024 + row];
      u32 dw = 0;
      dw = (u32)__builtin_amdgcn_cvt_pk_fp8_f32(acc[i][0][r] + bias,
                                                acc[i][1][r] + bias, (int)dw, false);
      dw = (u32)__builtin_amdgcn_cvt_pk_fp8_f32(acc[i][2][r] + bias,
                                                acc[i][3][r] + bias, (int)dw, true);
      *(u32*)((unsigned char*)V8 + ((size_t)b * C_ + row) * HW_ + cb + fr * 4) = dw;
    }
}

// P8[b][i][sigma-pos j] = fp8( PSCALE * exp(scale * q_i.k_j) ); MX-fp8 GEMM.
// XCD-aware 1-D grid: the 32 K-panel blocks sharing a Q row-panel are
// dispatch-adjacent on one XCD (QKt8 panels stay L2-hot per XCD).
__global__ void __launch_bounds__(256) sexp_gemm_kernel(const fp8_t* __restrict__ QKt8,
                                                        fp8_t* __restrict__ P8) {
  const int n   = blockIdx.x;            // 4096 blocks
  const int xcd = n & 7;
  const int p   = n >> 3;                // 0..511 within XCD
  const int xb  = p & 31;                // K panel (fastest -> share Q panel)
  const int grp = xcd * 16 + (p >> 5);   // 0..127 = (yb, b) combo
  const int yb  = grp & 31;              // Q panel
  const int b   = grp >> 5;              // batch

  const unsigned char* QKtb = (const unsigned char*)QKt8 + (size_t)b * HW_ * 1024;
  fp8_t* Pb = P8 + (size_t)b * HW_ * HW_;
  f32x4 acc[4][4]; zero_acc(acc);
  const unsigned char* A  = QKtb + (size_t)yb * 128 * 1024;        // Q rows
  const unsigned char* Bp = QKtb + 512 + (size_t)xb * 128 * 1024;  // K rows
  gemm_bt_mx<false>(A, Bp, 512, 1024, 1024, acc, nullptr);
  const int lane = threadIdx.x & 63, wave = threadIdx.x >> 6;
  const int wm = (wave >> 1) * 64, wn = (wave & 1) * 64;
  const int fr = lane & 15, q = lane >> 4;
  const int r0 = yb * 128 + wm + (q << 2);
  const int cb = xb * 128 + wn;          // j 64-group base
#pragma unroll
  for (int i = 0; i < 4; ++i)
#pragma unroll
    for (int r = 0; r < 4; ++r) {
      const int row = r0 + i * 16 + r;
      float e0 = __expf(acc[i][0][r] * SCALE_) * PSCALE_;
      float e1 = __expf(acc[i][1][r] * SCALE_) * PSCALE_;
      float e2 = __expf(acc[i][2][r] * SCALE_) * PSCALE_;
      float e3 = __expf(acc[i][3][r] * SCALE_) * PSCALE_;
      u32 dw = 0;
      dw = (u32)__builtin_amdgcn_cvt_pk_fp8_f32(e0, e1, (int)dw, false);
      dw = (u32)__builtin_amdgcn_cvt_pk_fp8_f32(e2, e3, (int)dw, true);
      *(u32*)((unsigned char*)Pb + (size_t)row * HW_ + cb + fr * 4) = dw;
    }
}

// hmT8[b][i][sigma-pos c] = fp8( 16 * (sum_j P8 * V8) / rowsum(P8) )
// MX-fp8 GEMM with ones-MFMA row sums; XCD-aware block remap for P L2 reuse.
__global__ void __launch_bounds__(256) pv_gemm_kernel(const fp8_t* __restrict__ P8,
                                                      const fp8_t* __restrict__ V8,
                                                      fp8_t* __restrict__ hmT8) {
  // decode swizzled block id: n = 512 blocks total
  const int n   = blockIdx.x;
  const int xcd = n & 7;           // XCD (round-robin heuristic)
  const int p   = n >> 3;          // 0..63, position within XCD
  const int xb  = p & 3;           // C panel (fastest -> adjacent blocks share P)
  const int grp = xcd * 16 + (p >> 2);  // 0..127 = (y,z) group
  const int yb  = grp & 31;        // HW panel
  const int b   = grp >> 5;        // batch

  const unsigned char* A  = (const unsigned char*)P8 + (size_t)b * HW_ * HW_ +
                            (size_t)yb * 128 * HW_;
  const unsigned char* Bp = (const unsigned char*)V8 + (size_t)b * C_ * HW_ +
                            (size_t)xb * 128 * HW_;
  fp8_t* hmTb = hmT8 + (size_t)b * HW_ * C_;

  f32x4 acc[4][4]; zero_acc(acc);
  f32x4 accl[4];
  {
    f32x4 z = {0.f, 0.f, 0.f, 0.f};
#pragma unroll
    for (int i = 0; i < 4; ++i) accl[i] = z;
  }
  gemm_bt_mx<true>(A, Bp, HW_, HW_, HW_, acc, accl);

  const int lane = threadIdx.x & 63, wave = threadIdx.x >> 6;
  const int wm = (wave >> 1) * 64, wn = (wave & 1) * 64;
  const int fr = lane & 15, q = lane >> 4;
  const int r0 = yb * 128 + wm + (q << 2);
  const int cb = xb * 128 + wn;   // c 64-group base (stored sigma-packed)
#pragma unroll
  for (int i = 0; i < 4; ++i)
#pragma unroll
    for (int r = 0; r < 4; ++r) {
      const int row = r0 + i * 16 + r;
      const float rl = 16.f / accl[i][r];   // x16 for fp8 range; undone by 2^-4 in proj
      u32 dw = 0;
      dw = (u32)__builtin_amdgcn_cvt_pk_fp8_f32(acc[i][0][r] * rl, acc[i][1][r] * rl, (int)dw, false);
      dw = (u32)__builtin_amdgcn_cvt_pk_fp8_f32(acc[i][2][r] * rl, acc[i][3][r] * rl, (int)dw, true);
      *(u32*)((unsigned char*)hmTb + (size_t)row * C_ + cb + fr * 4) = dw;
    }
}

// out[b][o][i] = x[b][o][i] + proj_b[o] + (wproj8*2^-4)(sigma) . (hmT8*2^-4)(sigma)
__global__ void __launch_bounds__(256) proj_gemm_kernel(const fp8_t* __restrict__ wproj8,
                                                        const fp8_t* __restrict__ hmT8,
                                                        const float* __restrict__ proj_b,
                                                        const float* __restrict__ x,
                                                        float* __restrict__ out) {
  const int b = blockIdx.z;
  f32x4 acc[4][4]; zero_acc(acc);
  const unsigned char* A  = (const unsigned char*)wproj8 + (size_t)blockIdx.y * 128 * C_;
  const unsigned char* Bp = (const unsigned char*)hmT8 + ((size_t)b * HW_ + blockIdx.x * 128) * C_;
  gemm_bt_mx<false, 0x7B, 0x7B>(A, Bp, C_, C_, C_, acc, nullptr);
  const int lane = threadIdx.x & 63, wave = threadIdx.x >> 6;
  const int wm = (wave >> 1) * 64, wn = (wave & 1) * 64;
  const int r0 = blockIdx.y * 128 + wm + ((lane >> 4) << 2);
  const int c0 = blockIdx.x * 128 + wn + (lane & 15);
#pragma unroll
  for (int i = 0; i < 4; ++i)
#pragma unroll
    for (int r = 0; r < 4; ++r) {
      const int row = r0 + i * 16 + r;
      const float bias = proj_b[row];
#pragma unroll
      for (int j = 0; j < 4; ++j) {
        const int col = c0 + j * 16;
        const size_t idx = ((size_t)b * C_ + row) * HW_ + col;
        out[idx] = x[idx] + bias + acc[i][j][r];
      }
    }
}

// ---------------- launch ----------------
// Workspace layout (bytes), total ~110 MB:
//   wqkv8  fp8 [1536][512] (x16)         786,432
//   wproj8 fp8 [512][512] (x16, sigma)   262,144
//   stats  f32 [128][2]                    1,024
//   xnT8   fp8 [4][4096][512]          8,388,608
//   QKt8   fp8 [4][4096][1024](sig)   16,777,216
//   V8     fp8 [4][512][4096] (sig)    8,388,608
//   hmT8   fp8 [4][4096][512] (x16,sig) 8,388,608
//   P8     fp8 [4][4096][4096](sig)   67,108,864
extern "C" void kernel_launch(void* const* d_in, const int* in_sizes, int n_in,
                              void* d_out, int out_size, void* d_ws, size_t ws_size,
                              hipStream_t stream) {
  const float* x      = (const float*)d_in[0];
  const float* norm_w = (const float*)d_in[1];
  const float* norm_b = (const float*)d_in[2];
  const float* qkv_w  = (const float*)d_in[3];
  const float* qkv_b  = (const float*)d_in[4];
  const float* proj_w = (const float*)d_in[5];
  const float* proj_b = (const float*)d_in[6];
  float* out = (float*)d_out;

  char* ws = (char*)d_ws;
  size_t o = 0;
  fp8_t* wqkv8  = (fp8_t*)(ws + o); o += (size_t)1536 * 512;
  fp8_t* wproj8 = (fp8_t*)(ws + o); o += (size_t)512 * 512;
  float* stats  = (float*)(ws + o); o += 128 * 2 * 4;
  fp8_t* xnT8   = (fp8_t*)(ws + o); o += (size_t)B_ * HW_ * C_;
  fp8_t* QKt8   = (fp8_t*)(ws + o); o += (size_t)B_ * HW_ * 1024;
  fp8_t* V8     = (fp8_t*)(ws + o); o += (size_t)B_ * C_ * HW_;
  fp8_t* hmT8   = (fp8_t*)(ws + o); o += (size_t)B_ * HW_ * C_;
  fp8_t* P8     = (fp8_t*)(ws + o); o += (size_t)B_ * HW_ * HW_;

  cast_w_kernel<<<1024, 256, 0, stream>>>(qkv_w, proj_w, wqkv8, wproj8);
  hipMemsetAsync(stats, 0, 128 * 2 * sizeof(float), stream);
  gn_partial_kernel<<<1024, 256, 0, stream>>>(x, stats);
  norm_tr_kernel<<<dim3(HW_ / 64, C_ / 64, B_), 256, 0, stream>>>(x, stats, norm_w, norm_b, xnT8);
  qk_gemm_kernel<<<dim3(1024 / 128, HW_ / 128, B_), 256, 0, stream>>>(xnT8, wqkv8, qkv_b, QKt8);
  v_gemm_kernel<<<dim3(HW_ / 128, C_ / 128, B_), 256, 0, stream>>>(wqkv8, xnT8, qkv_b, V8);
  sexp_gemm_kernel<<<4096, 256, 0, stream>>>(QKt8, P8);
  pv_gemm_kernel<<<512, 256, 0, stream>>>(P8, V8, hmT8);
  proj_gemm_kernel<<<dim3(HW_ / 128, C_ / 128, B_), 256, 0, stream>>>(
      wproj8, hmT8, proj_b, x, out);
}